// Round 1
// baseline (210.688 us; speedup 1.0000x reference)
//
#include <hip/hip_runtime.h>

#define LAMBDA_COORD 5.0f
#define LAMBDA_NOOBJ 0.5f

// cells: N*S*S = 16384*7*7 = 802816; preds 30 f32/cell, targets 25 f32/cell.

__global__ void zero_out_kernel(float* out, int n) {
    int i = blockIdx.x * blockDim.x + threadIdx.x;
    if (i < n) out[i] = 0.0f;
}

__global__ __launch_bounds__(256) void yolo_loss_kernel(
    const float* __restrict__ preds, const float* __restrict__ targets,
    float* __restrict__ out, int n_cells)
{
    __shared__ float s_pred[256 * 30];   // 30720 B
    __shared__ float s_targ[256 * 25];   // 25600 B
    __shared__ float s_part[4];

    const int tid = threadIdx.x;
    const int block_cell0 = blockIdx.x * 256;
    const int cells_here = min(256, n_cells - block_cell0);

    if (cells_here == 256) {
        // Block chunk byte offsets: block*30720 and block*25600 — both 16B-aligned.
        const float4* p4 = (const float4*)(preds + (size_t)block_cell0 * 30);
        const float4* t4 = (const float4*)(targets + (size_t)block_cell0 * 25);
        float4* sp4 = (float4*)s_pred;
        float4* st4 = (float4*)s_targ;
        for (int k = tid; k < 1920; k += 256) sp4[k] = p4[k];   // 256*30/4
        for (int k = tid; k < 1600; k += 256) st4[k] = t4[k];   // 256*25/4
    } else {
        for (int k = tid; k < cells_here * 30; k += 256)
            s_pred[k] = preds[(size_t)block_cell0 * 30 + k];
        for (int k = tid; k < cells_here * 25; k += 256)
            s_targ[k] = targets[(size_t)block_cell0 * 25 + k];
    }
    __syncthreads();

    float loss = 0.0f;
    if (tid < cells_here) {
        const float* p = s_pred + tid * 30;
        const float* t = s_targ + tid * 25;
        float p0 = p[0], p5 = p[5];
        // jnp.argmax picks first index on tie -> box1 only on strict greater.
        bool pick1 = p5 > p0;
        float b0 = pick1 ? p5   : p0;
        float b1 = pick1 ? p[6] : p[1];
        float b2 = pick1 ? p[7] : p[2];
        float b3 = pick1 ? p[8] : p[3];
        float b4 = pick1 ? p[9] : p[4];
        float t0 = t[0];
        float d1 = b1 - t[1], d2 = b2 - t[2], d3 = b3 - t[3], d4 = b4 - t[4];
        float box_loss = d1 * d1 + d2 * d2 + d3 * d3 + d4 * d4;
        float dpc = b0 - t0;
        float pc_loss = dpc * dpc;
        float class_loss = 0.0f;
        #pragma unroll
        for (int j = 0; j < 20; ++j) {
            float d = p[10 + j] - t[5 + j];
            class_loss += d * d;
        }
        float obj_term = LAMBDA_COORD * box_loss + pc_loss + class_loss;
        float noobj_term = LAMBDA_NOOBJ * (p0 * p0 + p5 * p5);
        loss = (t0 == 1.0f) ? obj_term : noobj_term;
    }

    // wave (64-lane) shuffle reduction
    #pragma unroll
    for (int off = 32; off > 0; off >>= 1)
        loss += __shfl_down(loss, off, 64);

    const int wave = tid >> 6;
    if ((tid & 63) == 0) s_part[wave] = loss;
    __syncthreads();
    if (tid == 0) {
        float s = s_part[0] + s_part[1] + s_part[2] + s_part[3];
        atomicAdd(out, s);
    }
}

extern "C" void kernel_launch(void* const* d_in, const int* in_sizes, int n_in,
                              void* d_out, int out_size, void* d_ws, size_t ws_size,
                              hipStream_t stream) {
    const float* preds   = (const float*)d_in[0];
    const float* targets = (const float*)d_in[1];
    float* out = (float*)d_out;

    const int n_cells = in_sizes[0] / 30;   // 802816

    // d_out is poisoned (0xAA) before every timed replay — zero it on-stream.
    zero_out_kernel<<<(out_size + 255) / 256, 256, 0, stream>>>(out, out_size);

    const int grid = (n_cells + 255) / 256; // 3136
    yolo_loss_kernel<<<grid, 256, 0, stream>>>(preds, targets, out, n_cells);
}